// Round 1
// baseline (2787.172 us; speedup 1.0000x reference)
//
#include <hip/hip_runtime.h>
#include <cstdint>
#include <cstddef>

// ---------------------------------------------------------------------------
// PointNet++ (B=8, N=4096, K=64, N1=2048, N2=512, r1=0.2, r2=0.4), fp32.
// Selection stages (FPS argmax, ball-query top-k) are computed with
// __f*_rn intrinsics in numpy's association order so selected index sets
// match the reference bit-exactly; MLP math uses fma freely.
// ---------------------------------------------------------------------------

static constexpr int Bc = 8;     // batch (clouds)
static constexpr int Np = 4096;  // points per cloud
static constexpr int Kn = 64;    // max neighbors
static constexpr int M1 = 2048;  // SA1 centers
static constexpr int M2 = 512;   // SA2 centers
static constexpr int LDX = 132;  // row stride of X = [x2 (128) | c2 (3) | pad]

#define DEVINL __device__ __forceinline__

// exact replication of np: ((dx*dx + dy*dy) + dz*dz), no fma contraction
DEVINL float d2_exact(float ax, float ay, float az, float bx, float by, float bz) {
    float dx = __fsub_rn(ax, bx);
    float dy = __fsub_rn(ay, by);
    float dz = __fsub_rn(az, bz);
    float xx = __fmul_rn(dx, dx);
    float yy = __fmul_rn(dy, dy);
    float zz = __fmul_rn(dz, dz);
    return __fadd_rn(__fadd_rn(xx, yy), zz);
}

DEVINL unsigned long long wave_max_u64(unsigned long long k) {
    #pragma unroll
    for (int o = 32; o > 0; o >>= 1) {
        unsigned long long other = __shfl_xor(k, o, 64);
        if (other > k) k = other;
    }
    return k;
}

// ---------------------------------------------------------------------------
// Farthest point sampling: one block (256 threads) per cloud. Sequential over
// ns-1 steps; minds+coords in registers, coords mirrored in LDS for the
// broadcast of the selected point. Key packs (f32 bits << 32) | (~idx) so the
// u64 max reduce == argmax with first-index tie-break (d2 >= 0 -> monotonic).
// ---------------------------------------------------------------------------
template <int N>
__global__ __launch_bounds__(256)
void fps_kernel(const float* __restrict__ pts, int ns,
                int* __restrict__ idx_out, float* __restrict__ cent) {
    constexpr int PT = N / 256;
    __shared__ float sx_[N], sy_[N], sz_[N];
    __shared__ unsigned long long pbuf[2][4];
    const int b = blockIdx.x;
    const int t = threadIdx.x;
    const int wid = t >> 6;
    const int lane = t & 63;
    const float* base = pts + (size_t)b * N * 3;

    float px[PT], py[PT], pz[PT], mind[PT];
    #pragma unroll
    for (int j = 0; j < PT; ++j) {
        int p = j * 256 + t;
        px[j] = base[p * 3 + 0];
        py[j] = base[p * 3 + 1];
        pz[j] = base[p * 3 + 2];
        sx_[p] = px[j]; sy_[p] = py[j]; sz_[p] = pz[j];
    }
    float x0 = base[0], y0 = base[1], z0 = base[2];
    float bv = -1.0f; int bi = 0;
    #pragma unroll
    for (int j = 0; j < PT; ++j) {
        float d = d2_exact(px[j], py[j], pz[j], x0, y0, z0);
        mind[j] = d;
        if (d > bv) { bv = d; bi = j * 256 + t; }
    }
    unsigned long long key = ((unsigned long long)__float_as_uint(bv) << 32)
                           | (unsigned long long)(0xFFFFFFFFu - (unsigned)bi);
    key = wave_max_u64(key);
    if (lane == 0) pbuf[1][wid] = key;
    if (t == 0) {
        idx_out[(size_t)b * ns] = 0;
        cent[((size_t)b * ns) * 3 + 0] = x0;
        cent[((size_t)b * ns) * 3 + 1] = y0;
        cent[((size_t)b * ns) * 3 + 2] = z0;
    }
    for (int s = 1; s < ns; ++s) {
        __syncthreads();  // double-buffered partials -> one barrier per step
        unsigned long long k0 = pbuf[s & 1][0];
        unsigned long long k1 = pbuf[s & 1][1];
        unsigned long long k2 = pbuf[s & 1][2];
        unsigned long long k3 = pbuf[s & 1][3];
        unsigned long long ka = k0 > k1 ? k0 : k1;
        unsigned long long kb = k2 > k3 ? k2 : k3;
        unsigned long long km = ka > kb ? ka : kb;
        int idx = (int)(0xFFFFFFFFu - (unsigned)(km & 0xFFFFFFFFull));
        float cx = sx_[idx], cy = sy_[idx], cz = sz_[idx];
        if (t == 0) {
            idx_out[(size_t)b * ns + s] = idx;
            cent[((size_t)b * ns + s) * 3 + 0] = cx;
            cent[((size_t)b * ns + s) * 3 + 1] = cy;
            cent[((size_t)b * ns + s) * 3 + 2] = cz;
        }
        bv = -1.0f; bi = 0;
        #pragma unroll
        for (int j = 0; j < PT; ++j) {
            float d = d2_exact(px[j], py[j], pz[j], cx, cy, cz);
            float m = fminf(mind[j], d);
            mind[j] = m;
            if (m > bv) { bv = m; bi = j * 256 + t; }  // strict > keeps lowest idx
        }
        key = ((unsigned long long)__float_as_uint(bv) << 32)
            | (unsigned long long)(0xFFFFFFFFu - (unsigned)bi);
        key = wave_max_u64(key);
        if (lane == 0) pbuf[(s + 1) & 1][wid] = key;
    }
}

// ---------------------------------------------------------------------------
// Ball query: one wave per center. d2 per lane in registers; wave-wide counts
// via ballot+popc. If >K in radius, exact kth-smallest via binary search on
// float bit patterns, ties broken by smallest index (== lax.top_k semantics).
// Output: Kn indices per center, -1 for invalid slots.
// ---------------------------------------------------------------------------
template <int NPT>
__global__ __launch_bounds__(256)
void bq_kernel(const float* __restrict__ pts, const float* __restrict__ ctr,
               int mshift, float r2, int* __restrict__ nbr) {
    constexpr int CH = NPT / 64;
    const int lane = threadIdx.x & 63;
    int w = __builtin_amdgcn_readfirstlane((int)(blockIdx.x * 4 + (threadIdx.x >> 6)));
    const int b = w >> mshift;
    const float* pb = pts + (size_t)b * NPT * 3;
    const float* cp = ctr + (size_t)w * 3;
    float cx = cp[0], cy = cp[1], cz = cp[2];
    const unsigned r2b = __float_as_uint(r2);

    unsigned ub[CH];
    int cnt = 0;
    #pragma unroll
    for (int j = 0; j < CH; ++j) {
        int p = j * 64 + lane;
        float d = d2_exact(pb[p * 3 + 0], pb[p * 3 + 1], pb[p * 3 + 2], cx, cy, cz);
        ub[j] = __float_as_uint(d);   // d >= 0 -> bits monotonic
        cnt += __popcll(__ballot(ub[j] <= r2b));
    }
    int* out = nbr + (size_t)w * Kn;
    const unsigned long long lml = (1ull << lane) - 1ull;

    if (cnt <= Kn) {
        int basep = 0;
        #pragma unroll
        for (int j = 0; j < CH; ++j) {
            bool v = ub[j] <= r2b;
            unsigned long long mk = __ballot(v);
            if (v) out[basep + __popcll(mk & lml)] = j * 64 + lane;
            basep += __popcll(mk);
        }
        if (lane >= cnt) out[lane] = -1;
    } else {
        // kth smallest (k=64): smallest t with countLE(t) >= 64
        unsigned lo = 0, hi = r2b;
        while (lo < hi) {
            unsigned mid = lo + ((hi - lo) >> 1);
            int c = 0;
            #pragma unroll
            for (int j = 0; j < CH; ++j) c += __popcll(__ballot(ub[j] <= mid));
            if (c >= Kn) hi = mid; else lo = mid + 1;
        }
        const unsigned tt = lo;
        int cntLess = 0;
        #pragma unroll
        for (int j = 0; j < CH; ++j) cntLess += __popcll(__ballot(ub[j] < tt));
        const int quota = Kn - cntLess;
        int baseLt = 0, eqseen = 0;
        #pragma unroll
        for (int j = 0; j < CH; ++j) {
            bool lt = ub[j] < tt;
            bool eq = ub[j] == tt;
            unsigned long long mlt = __ballot(lt);
            unsigned long long meq = __ballot(eq);
            if (lt) out[baseLt + __popcll(mlt & lml)] = j * 64 + lane;
            if (eq) {
                int rr = eqseen + __popcll(meq & lml);
                if (rr < quota) out[cntLess + rr] = j * 64 + lane;
            }
            baseLt += __popcll(mlt);
            eqseen += __popcll(meq);
        }
    }
}

// ---------------------------------------------------------------------------
// MLP1 (SA1): wave per center, lane per neighbor. 3 -> 64 relu -> 64 relu,
// masked max over neighbors via shfl_xor reduce. Weights pre-transposed:
// w1aT[h] = {w1a[0][h], w1a[1][h], w1a[2][h], b1a[h]}, w1bT[c][h].
// ---------------------------------------------------------------------------
__global__ __launch_bounds__(256)
void mlp1_kernel(const float* __restrict__ pos, const float* __restrict__ c1,
                 const int* __restrict__ nbr, const float* __restrict__ w1aT,
                 const float* __restrict__ w1bT, const float* __restrict__ b1b,
                 float* __restrict__ x1) {
    const int lane = threadIdx.x & 63;
    int w = __builtin_amdgcn_readfirstlane((int)(blockIdx.x * 4 + (threadIdx.x >> 6)));
    const int b = w >> 11;
    const int ii = nbr[(size_t)w * Kn + lane];
    const bool valid = ii >= 0;
    const int i2 = valid ? ii : 0;
    const float* pp = pos + ((size_t)b * Np + i2) * 3;
    const float* cc = c1 + (size_t)w * 3;
    float rx = pp[0] - cc[0], ry = pp[1] - cc[1], rz = pp[2] - cc[2];
    float h1[64];
    #pragma unroll
    for (int h = 0; h < 64; ++h) {
        float4 wv = ((const float4*)w1aT)[h];
        float a = fmaf(rx, wv.x, fmaf(ry, wv.y, fmaf(rz, wv.z, wv.w)));
        h1[h] = fmaxf(a, 0.0f);
    }
    float* orow = x1 + (size_t)w * 64;
    for (int c4 = 0; c4 < 16; ++c4) {
        float v4[4];
        #pragma unroll
        for (int cq = 0; cq < 4; ++cq) {
            int c = c4 * 4 + cq;
            float acc = b1b[c];
            const float4* wr = (const float4*)(w1bT + (size_t)c * 64);
            #pragma unroll
            for (int q = 0; q < 16; ++q) {
                float4 wv = wr[q];
                acc = fmaf(h1[4 * q + 0], wv.x, acc);
                acc = fmaf(h1[4 * q + 1], wv.y, acc);
                acc = fmaf(h1[4 * q + 2], wv.z, acc);
                acc = fmaf(h1[4 * q + 3], wv.w, acc);
            }
            float v = fmaxf(acc, 0.0f);
            v = valid ? v : -__builtin_inff();
            #pragma unroll
            for (int o = 32; o > 0; o >>= 1) v = fmaxf(v, __shfl_xor(v, o, 64));
            v4[cq] = v;
        }
        if (lane == 0)
            ((float4*)orow)[c4] = make_float4(v4[0], v4[1], v4[2], v4[3]);
    }
}

// ---------------------------------------------------------------------------
// MLP2 (SA2): wave per center, lane per neighbor. [x1(64) | relpos(3)] -> 128
// relu -> 128 relu, masked max; writes x2 into X rows (cols 0..127).
// w2aT[h][0..66]=w2a[:,h], [67]=b2a[h], row stride 80. w2bT[c][h].
// ---------------------------------------------------------------------------
__global__ __launch_bounds__(256)
void mlp2_kernel(const float* __restrict__ x1, const float* __restrict__ c1,
                 const float* __restrict__ c2, const int* __restrict__ nbr2,
                 const float* __restrict__ w2aT, const float* __restrict__ w2bT,
                 const float* __restrict__ b2b, float* __restrict__ X) {
    const int lane = threadIdx.x & 63;
    int w = __builtin_amdgcn_readfirstlane((int)(blockIdx.x * 4 + (threadIdx.x >> 6)));
    const int b = w >> 9;
    const int ii = nbr2[(size_t)w * Kn + lane];
    const bool valid = ii >= 0;
    const int i2 = valid ? ii : 0;

    float x[68];
    const float4* xr = (const float4*)(x1 + ((size_t)b * M1 + i2) * 64);
    #pragma unroll
    for (int q = 0; q < 16; ++q) {
        float4 v = xr[q];
        x[4 * q + 0] = v.x; x[4 * q + 1] = v.y;
        x[4 * q + 2] = v.z; x[4 * q + 3] = v.w;
    }
    const float* cc = c2 + (size_t)w * 3;
    const float* cp = c1 + ((size_t)b * M1 + i2) * 3;
    x[64] = cp[0] - cc[0];
    x[65] = cp[1] - cc[1];
    x[66] = cp[2] - cc[2];
    x[67] = 0.0f;

    float h1[128];
    #pragma unroll
    for (int h = 0; h < 128; ++h) {
        const float4* r4 = (const float4*)(w2aT + (size_t)h * 80);
        float acc = 0.0f;
        #pragma unroll
        for (int q = 0; q < 16; ++q) {
            float4 wv = r4[q];
            acc = fmaf(x[4 * q + 0], wv.x, acc);
            acc = fmaf(x[4 * q + 1], wv.y, acc);
            acc = fmaf(x[4 * q + 2], wv.z, acc);
            acc = fmaf(x[4 * q + 3], wv.w, acc);
        }
        float4 tl = r4[16];   // w64, w65, w66, bias
        acc = fmaf(x[64], tl.x, acc);
        acc = fmaf(x[65], tl.y, acc);
        acc = fmaf(x[66], tl.z, acc);
        acc += tl.w;
        h1[h] = fmaxf(acc, 0.0f);
    }
    float* orow = X + (size_t)w * LDX;
    for (int c4 = 0; c4 < 32; ++c4) {
        float v4[4];
        #pragma unroll
        for (int cq = 0; cq < 4; ++cq) {
            int c = c4 * 4 + cq;
            float acc = b2b[c];
            const float4* wr = (const float4*)(w2bT + (size_t)c * 128);
            #pragma unroll
            for (int q = 0; q < 32; ++q) {
                float4 wv = wr[q];
                acc = fmaf(h1[4 * q + 0], wv.x, acc);
                acc = fmaf(h1[4 * q + 1], wv.y, acc);
                acc = fmaf(h1[4 * q + 2], wv.z, acc);
                acc = fmaf(h1[4 * q + 3], wv.w, acc);
            }
            float v = fmaxf(acc, 0.0f);
            v = valid ? v : -__builtin_inff();
            #pragma unroll
            for (int o = 32; o > 0; o >>= 1) v = fmaxf(v, __shfl_xor(v, o, 64));
            v4[cq] = v;
        }
        if (lane == 0) {
            orow[c4 * 4 + 0] = v4[0]; orow[c4 * 4 + 1] = v4[1];
            orow[c4 * 4 + 2] = v4[2]; orow[c4 * 4 + 3] = v4[3];
        }
    }
}

// ---------------------------------------------------------------------------
// X[:,128..130] = c2
// ---------------------------------------------------------------------------
__global__ __launch_bounds__(256)
void writec2_kernel(const float* __restrict__ c2, float* __restrict__ X) {
    int i = blockIdx.x * 256 + threadIdx.x;
    if (i < Bc * M2 * 3) {
        int w = i / 3, d = i - w * 3;
        X[(size_t)w * LDX + 128 + d] = c2[i];
    }
}

// ---------------------------------------------------------------------------
// GEMM1: H[r][c] = relu(b3a[c] + sum_i X[r][i] * w3a[i][c]), K=131.
// Block per row (uniform X row -> scalar loads), thread per channel.
// ---------------------------------------------------------------------------
__global__ __launch_bounds__(256)
void gemm1_kernel(const float* __restrict__ X, const float* __restrict__ w3a,
                  const float* __restrict__ b3a, float* __restrict__ H) {
    const int r = blockIdx.x;
    const int c = threadIdx.x;
    const float* xr = X + (size_t)r * LDX;
    float acc = b3a[c];
    for (int i = 0; i < 131; ++i)
        acc = fmaf(xr[i], w3a[(size_t)i * 256 + c], acc);
    H[(size_t)r * 256 + c] = fmaxf(acc, 0.0f);
}

// ---------------------------------------------------------------------------
// GEMM2 fused with per-tile row max: 32x64 tile, BK=32, thread = 4 rows x 2
// cols. Epilogue maxes over the 32 rows (all within one cloud) -> partial.
// Bias is added later (uniform per column, commutes with max).
// ---------------------------------------------------------------------------
__global__ __launch_bounds__(256)
void gemm2_kernel(const float* __restrict__ H, const float* __restrict__ w3b,
                  float* __restrict__ part) {
    __shared__ float As[32][33];
    __shared__ float Bs[32][64];
    __shared__ float red[8][64];
    const int bidx = blockIdx.x;
    const int nt = bidx & 15;
    const int mt = (bidx >> 4) & 15;
    const int b = bidx >> 8;
    const int row0 = b * M2 + mt * 32;
    const int col0 = nt * 64;
    const int t = threadIdx.x;
    const int rg = t >> 5, cg = t & 31;

    float acc[4][2] = {{0.f, 0.f}, {0.f, 0.f}, {0.f, 0.f}, {0.f, 0.f}};
    for (int k0 = 0; k0 < 256; k0 += 32) {
        #pragma unroll
        for (int q = 0; q < 4; ++q) {
            int id = t + q * 256;
            As[id >> 5][id & 31] = H[(size_t)(row0 + (id >> 5)) * 256 + k0 + (id & 31)];
        }
        #pragma unroll
        for (int q = 0; q < 8; ++q) {
            int id = t + q * 256;
            Bs[id >> 6][id & 63] = w3b[(size_t)(k0 + (id >> 6)) * 1024 + col0 + (id & 63)];
        }
        __syncthreads();
        #pragma unroll
        for (int kk = 0; kk < 32; ++kk) {
            float b0 = Bs[kk][cg * 2 + 0];
            float b1 = Bs[kk][cg * 2 + 1];
            #pragma unroll
            for (int j = 0; j < 4; ++j) {
                float a = As[rg * 4 + j][kk];
                acc[j][0] = fmaf(a, b0, acc[j][0]);
                acc[j][1] = fmaf(a, b1, acc[j][1]);
            }
        }
        __syncthreads();
    }
    float m0 = fmaxf(fmaxf(acc[0][0], acc[1][0]), fmaxf(acc[2][0], acc[3][0]));
    float m1 = fmaxf(fmaxf(acc[0][1], acc[1][1]), fmaxf(acc[2][1], acc[3][1]));
    red[rg][cg * 2 + 0] = m0;
    red[rg][cg * 2 + 1] = m1;
    __syncthreads();
    if (t < 64) {
        float v = red[0][t];
        #pragma unroll
        for (int q = 1; q < 8; ++q) v = fmaxf(v, red[q][t]);
        part[((size_t)b * 16 + mt) * 1024 + col0 + t] = v;
    }
}

// ---------------------------------------------------------------------------
// Final max over the 16 m-tiles per cloud + bias (no relu on last layer).
// ---------------------------------------------------------------------------
__global__ __launch_bounds__(256)
void rmax_kernel(const float* __restrict__ part, const float* __restrict__ b3b,
                 float* __restrict__ out) {
    int i = blockIdx.x * 256 + threadIdx.x;  // 8192 = B*1024
    int b = i >> 10, c = i & 1023;
    float v = -__builtin_inff();
    #pragma unroll
    for (int tt = 0; tt < 16; ++tt)
        v = fmaxf(v, part[((size_t)b * 16 + tt) * 1024 + c]);
    out[i] = v + b3b[c];
}

// ---------------------------------------------------------------------------
// Weight transposes (recomputed every call; inputs are restored each run).
// ---------------------------------------------------------------------------
__global__ __launch_bounds__(256)
void prep_kernel(const float* __restrict__ w1a, const float* __restrict__ b1a,
                 const float* __restrict__ w1b, const float* __restrict__ w2a,
                 const float* __restrict__ b2a, const float* __restrict__ w2b,
                 float* __restrict__ w1aT, float* __restrict__ w1bT,
                 float* __restrict__ w2aT, float* __restrict__ w2bT) {
    int i = blockIdx.x * 256 + threadIdx.x;  // 0..16383
    if (i < 64 * 4) {
        int h = i >> 2, d = i & 3;
        w1aT[i] = (d < 3) ? w1a[d * 64 + h] : b1a[h];
    }
    if (i < 64 * 64) {
        int c = i >> 6, h = i & 63;
        w1bT[i] = w1b[h * 64 + c];
    }
    if (i < 128 * 80) {
        int h = i / 80, d = i - h * 80;
        w2aT[i] = (d < 67) ? w2a[d * 128 + h] : ((d == 67) ? b2a[h] : 0.0f);
    }
    {
        int c = i >> 7, h = i & 127;
        w2bT[i] = w2b[h * 128 + c];
    }
}

// ---------------------------------------------------------------------------
extern "C" void kernel_launch(void* const* d_in, const int* in_sizes, int n_in,
                              void* d_out, int out_size, void* d_ws, size_t ws_size,
                              hipStream_t stream) {
    const float* pos = (const float*)d_in[0];
    const float* w1a = (const float*)d_in[1];
    const float* b1a = (const float*)d_in[2];
    const float* w1b = (const float*)d_in[3];
    const float* b1b = (const float*)d_in[4];
    const float* w2a = (const float*)d_in[5];
    const float* b2a = (const float*)d_in[6];
    const float* w2b = (const float*)d_in[7];
    const float* b2b = (const float*)d_in[8];
    const float* w3a = (const float*)d_in[9];
    const float* b3a = (const float*)d_in[10];
    const float* w3b = (const float*)d_in[11];
    const float* b3b = (const float*)d_in[12];
    float* out = (float*)d_out;

    char* ws = (char*)d_ws;
    size_t off = 0;
    auto alloc = [&](size_t bytes) -> char* {
        char* p = ws + off;
        off += (bytes + 255) & ~(size_t)255;
        return p;
    };
    float* c1   = (float*)alloc(sizeof(float) * Bc * M1 * 3);
    float* c2   = (float*)alloc(sizeof(float) * Bc * M2 * 3);
    int*   idx1 = (int*)alloc(sizeof(int) * Bc * M1);
    int*   idx2 = (int*)alloc(sizeof(int) * Bc * M2);
    int*   nbr1 = (int*)alloc(sizeof(int) * Bc * M1 * Kn);
    int*   nbr2 = (int*)alloc(sizeof(int) * Bc * M2 * Kn);
    float* x1   = (float*)alloc(sizeof(float) * Bc * M1 * 64);
    float* X    = (float*)alloc(sizeof(float) * Bc * M2 * LDX);
    float* H    = (float*)alloc(sizeof(float) * Bc * M2 * 256);
    float* part = (float*)alloc(sizeof(float) * Bc * 16 * 1024);
    float* w1aT = (float*)alloc(sizeof(float) * 64 * 4);
    float* w1bT = (float*)alloc(sizeof(float) * 64 * 64);
    float* w2aT = (float*)alloc(sizeof(float) * 128 * 80);
    float* w2bT = (float*)alloc(sizeof(float) * 128 * 128);

    prep_kernel<<<dim3(64), dim3(256), 0, stream>>>(w1a, b1a, w1b, w2a, b2a, w2b,
                                                    w1aT, w1bT, w2aT, w2bT);
    fps_kernel<Np><<<dim3(Bc), dim3(256), 0, stream>>>(pos, M1, idx1, c1);
    bq_kernel<Np><<<dim3(Bc * M1 / 4), dim3(256), 0, stream>>>(
        pos, c1, 11, (float)(0.2 * 0.2), nbr1);
    mlp1_kernel<<<dim3(Bc * M1 / 4), dim3(256), 0, stream>>>(
        pos, c1, nbr1, w1aT, w1bT, b1b, x1);
    fps_kernel<M1><<<dim3(Bc), dim3(256), 0, stream>>>(c1, M2, idx2, c2);
    bq_kernel<M1><<<dim3(Bc * M2 / 4), dim3(256), 0, stream>>>(
        c1, c2, 9, (float)(0.4 * 0.4), nbr2);
    mlp2_kernel<<<dim3(Bc * M2 / 4), dim3(256), 0, stream>>>(
        x1, c1, c2, nbr2, w2aT, w2bT, b2b, X);
    writec2_kernel<<<dim3(48), dim3(256), 0, stream>>>(c2, X);
    gemm1_kernel<<<dim3(Bc * M2), dim3(256), 0, stream>>>(X, w3a, b3a, H);
    gemm2_kernel<<<dim3(Bc * 16 * 16), dim3(256), 0, stream>>>(H, w3b, part);
    rmax_kernel<<<dim3(32), dim3(256), 0, stream>>>(part, b3b, out);
}

// Round 2
// 2629.729 us; speedup vs baseline: 1.0599x; 1.0599x over previous
//
#include <hip/hip_runtime.h>
#include <cstdint>
#include <cstddef>

// ---------------------------------------------------------------------------
// PointNet++ (B=8, N=4096, K=64, N1=2048, N2=512, r1=0.2, r2=0.4), fp32.
// Selection stages (FPS argmax, ball-query top-k) are computed with
// __f*_rn intrinsics in numpy's association order so selected index sets
// match the reference bit-exactly; MLP math uses fma freely.
// R1: FPS restructured — DPP wave reduce (VALU pipe, not LDS swizzle chain),
// 512-thread blocks (PT halved). FPS is a serial 2047-step dependence chain;
// everything here is latency, not throughput.
// ---------------------------------------------------------------------------

static constexpr int Bc = 8;     // batch (clouds)
static constexpr int Np = 4096;  // points per cloud
static constexpr int Kn = 64;    // max neighbors
static constexpr int M1 = 2048;  // SA1 centers
static constexpr int M2 = 512;   // SA2 centers
static constexpr int LDX = 132;  // row stride of X = [x2 (128) | c2 (3) | pad]

#define DEVINL __device__ __forceinline__

// exact replication of np: ((dx*dx + dy*dy) + dz*dz), no fma contraction
DEVINL float d2_exact(float ax, float ay, float az, float bx, float by, float bz) {
    float dx = __fsub_rn(ax, bx);
    float dy = __fsub_rn(ay, by);
    float dz = __fsub_rn(az, bz);
    float xx = __fmul_rn(dx, dx);
    float yy = __fmul_rn(dy, dy);
    float zz = __fmul_rn(dz, dz);
    return __fadd_rn(__fadd_rn(xx, yy), zz);
}

// ---------------------------------------------------------------------------
// DPP-based wave64 max-reduce of a u64 key. Keys are always > 0 here
// (value bits >= 0, ~idx > 0), so 0 is a safe identity for lanes the DPP
// shift/mask leaves unwritten (old = 0, bound_ctrl = true).
// After the 6 stages, lane 63 holds the wave-wide max.
// ---------------------------------------------------------------------------
template <int CTRL, int RM, int BM>
DEVINL unsigned long long dpp_max_step(unsigned long long k) {
    unsigned lo = (unsigned)k, hi = (unsigned)(k >> 32);
    unsigned slo = (unsigned)__builtin_amdgcn_update_dpp(0, (int)lo, CTRL, RM, BM, true);
    unsigned shi = (unsigned)__builtin_amdgcn_update_dpp(0, (int)hi, CTRL, RM, BM, true);
    unsigned long long s = ((unsigned long long)shi << 32) | (unsigned long long)slo;
    return s > k ? s : k;
}

DEVINL unsigned long long wave_max_u64_dpp(unsigned long long k) {
    k = dpp_max_step<0x111, 0xf, 0xf>(k);  // row_shr:1
    k = dpp_max_step<0x112, 0xf, 0xf>(k);  // row_shr:2
    k = dpp_max_step<0x114, 0xf, 0xf>(k);  // row_shr:4
    k = dpp_max_step<0x118, 0xf, 0xf>(k);  // row_shr:8  -> lane 15 of each row has row max
    k = dpp_max_step<0x142, 0xa, 0xf>(k);  // row_bcast:15 -> rows 1,3
    k = dpp_max_step<0x143, 0xc, 0xf>(k);  // row_bcast:31 -> rows 2,3; lane 63 = wave max
    return k;
}

// ---------------------------------------------------------------------------
// Farthest point sampling: one block (NT=512 threads, 8 waves) per cloud.
// Sequential over ns-1 steps; minds+coords in registers, coords mirrored in
// LDS for the broadcast of the selected point. Key packs
// (f32 bits << 32) | (~idx) so u64 max == argmax with first-index tie-break
// (d2 >= 0 -> bits monotonic). Per-wave DPP reduce -> lane 63 writes an 8B
// partial; double-buffered partials keep it to ONE barrier per step.
// ---------------------------------------------------------------------------
template <int N>
__global__ __launch_bounds__(512)
void fps_kernel(const float* __restrict__ pts, int ns,
                int* __restrict__ idx_out, float* __restrict__ cent) {
    constexpr int NT = 512;
    constexpr int NW = NT / 64;
    constexpr int PT = N / NT;
    __shared__ float sx_[N], sy_[N], sz_[N];
    __shared__ alignas(16) unsigned long long pbuf[2][NW];
    const int b = blockIdx.x;
    const int t = threadIdx.x;
    const int wid = t >> 6;
    const int lane = t & 63;
    const float* base = pts + (size_t)b * N * 3;

    float px[PT], py[PT], pz[PT], mind[PT];
    #pragma unroll
    for (int j = 0; j < PT; ++j) {
        int p = j * NT + t;
        px[j] = base[p * 3 + 0];
        py[j] = base[p * 3 + 1];
        pz[j] = base[p * 3 + 2];
        sx_[p] = px[j]; sy_[p] = py[j]; sz_[p] = pz[j];
    }
    float x0 = base[0], y0 = base[1], z0 = base[2];
    float bv = -1.0f; int bi = 0;
    #pragma unroll
    for (int j = 0; j < PT; ++j) {
        float d = d2_exact(px[j], py[j], pz[j], x0, y0, z0);
        mind[j] = d;
        if (d > bv) { bv = d; bi = j * NT + t; }
    }
    unsigned long long key = ((unsigned long long)__float_as_uint(bv) << 32)
                           | (unsigned long long)(0xFFFFFFFFu - (unsigned)bi);
    key = wave_max_u64_dpp(key);
    if (lane == 63) pbuf[1][wid] = key;
    if (t == 0) {
        idx_out[(size_t)b * ns] = 0;
        cent[((size_t)b * ns) * 3 + 0] = x0;
        cent[((size_t)b * ns) * 3 + 1] = y0;
        cent[((size_t)b * ns) * 3 + 2] = z0;
    }
    for (int s = 1; s < ns; ++s) {
        __syncthreads();  // double-buffered partials -> one barrier per step
        // combine NW=8 partials: 4 overlapped 16B LDS loads + 7 u64 maxes
        const ulonglong2* pb2 = (const ulonglong2*)pbuf[s & 1];
        ulonglong2 q0 = pb2[0], q1 = pb2[1], q2 = pb2[2], q3 = pb2[3];
        unsigned long long a0 = q0.x > q0.y ? q0.x : q0.y;
        unsigned long long a1 = q1.x > q1.y ? q1.x : q1.y;
        unsigned long long a2 = q2.x > q2.y ? q2.x : q2.y;
        unsigned long long a3 = q3.x > q3.y ? q3.x : q3.y;
        unsigned long long ka = a0 > a1 ? a0 : a1;
        unsigned long long kb = a2 > a3 ? a2 : a3;
        unsigned long long km = ka > kb ? ka : kb;
        int idx = (int)(0xFFFFFFFFu - (unsigned)(km & 0xFFFFFFFFull));
        float cx = sx_[idx], cy = sy_[idx], cz = sz_[idx];
        if (t == 0) {
            idx_out[(size_t)b * ns + s] = idx;
            cent[((size_t)b * ns + s) * 3 + 0] = cx;
            cent[((size_t)b * ns + s) * 3 + 1] = cy;
            cent[((size_t)b * ns + s) * 3 + 2] = cz;
        }
        bv = -1.0f; bi = 0;
        #pragma unroll
        for (int j = 0; j < PT; ++j) {
            float d = d2_exact(px[j], py[j], pz[j], cx, cy, cz);
            float m = fminf(mind[j], d);
            mind[j] = m;
            if (m > bv) { bv = m; bi = j * NT + t; }  // strict > keeps lowest idx
        }
        key = ((unsigned long long)__float_as_uint(bv) << 32)
            | (unsigned long long)(0xFFFFFFFFu - (unsigned)bi);
        key = wave_max_u64_dpp(key);
        if (lane == 63) pbuf[(s + 1) & 1][wid] = key;
    }
}

// ---------------------------------------------------------------------------
// Ball query: one wave per center. d2 per lane in registers; wave-wide counts
// via ballot+popc. If >K in radius, exact kth-smallest via binary search on
// float bit patterns, ties broken by smallest index (== lax.top_k semantics).
// Output: Kn indices per center, -1 for invalid slots.
// ---------------------------------------------------------------------------
template <int NPT>
__global__ __launch_bounds__(256)
void bq_kernel(const float* __restrict__ pts, const float* __restrict__ ctr,
               int mshift, float r2, int* __restrict__ nbr) {
    constexpr int CH = NPT / 64;
    const int lane = threadIdx.x & 63;
    int w = __builtin_amdgcn_readfirstlane((int)(blockIdx.x * 4 + (threadIdx.x >> 6)));
    const int b = w >> mshift;
    const float* pb = pts + (size_t)b * NPT * 3;
    const float* cp = ctr + (size_t)w * 3;
    float cx = cp[0], cy = cp[1], cz = cp[2];
    const unsigned r2b = __float_as_uint(r2);

    unsigned ub[CH];
    int cnt = 0;
    #pragma unroll
    for (int j = 0; j < CH; ++j) {
        int p = j * 64 + lane;
        float d = d2_exact(pb[p * 3 + 0], pb[p * 3 + 1], pb[p * 3 + 2], cx, cy, cz);
        ub[j] = __float_as_uint(d);   // d >= 0 -> bits monotonic
        cnt += __popcll(__ballot(ub[j] <= r2b));
    }
    int* out = nbr + (size_t)w * Kn;
    const unsigned long long lml = (1ull << lane) - 1ull;

    if (cnt <= Kn) {
        int basep = 0;
        #pragma unroll
        for (int j = 0; j < CH; ++j) {
            bool v = ub[j] <= r2b;
            unsigned long long mk = __ballot(v);
            if (v) out[basep + __popcll(mk & lml)] = j * 64 + lane;
            basep += __popcll(mk);
        }
        if (lane >= cnt) out[lane] = -1;
    } else {
        // kth smallest (k=64): smallest t with countLE(t) >= 64
        unsigned lo = 0, hi = r2b;
        while (lo < hi) {
            unsigned mid = lo + ((hi - lo) >> 1);
            int c = 0;
            #pragma unroll
            for (int j = 0; j < CH; ++j) c += __popcll(__ballot(ub[j] <= mid));
            if (c >= Kn) hi = mid; else lo = mid + 1;
        }
        const unsigned tt = lo;
        int cntLess = 0;
        #pragma unroll
        for (int j = 0; j < CH; ++j) cntLess += __popcll(__ballot(ub[j] < tt));
        const int quota = Kn - cntLess;
        int baseLt = 0, eqseen = 0;
        #pragma unroll
        for (int j = 0; j < CH; ++j) {
            bool lt = ub[j] < tt;
            bool eq = ub[j] == tt;
            unsigned long long mlt = __ballot(lt);
            unsigned long long meq = __ballot(eq);
            if (lt) out[baseLt + __popcll(mlt & lml)] = j * 64 + lane;
            if (eq) {
                int rr = eqseen + __popcll(meq & lml);
                if (rr < quota) out[cntLess + rr] = j * 64 + lane;
            }
            baseLt += __popcll(mlt);
            eqseen += __popcll(meq);
        }
    }
}

// ---------------------------------------------------------------------------
// MLP1 (SA1): wave per center, lane per neighbor. 3 -> 64 relu -> 64 relu,
// masked max over neighbors via shfl_xor reduce. Weights pre-transposed:
// w1aT[h] = {w1a[0][h], w1a[1][h], w1a[2][h], b1a[h]}, w1bT[c][h].
// ---------------------------------------------------------------------------
__global__ __launch_bounds__(256)
void mlp1_kernel(const float* __restrict__ pos, const float* __restrict__ c1,
                 const int* __restrict__ nbr, const float* __restrict__ w1aT,
                 const float* __restrict__ w1bT, const float* __restrict__ b1b,
                 float* __restrict__ x1) {
    const int lane = threadIdx.x & 63;
    int w = __builtin_amdgcn_readfirstlane((int)(blockIdx.x * 4 + (threadIdx.x >> 6)));
    const int b = w >> 11;
    const int ii = nbr[(size_t)w * Kn + lane];
    const bool valid = ii >= 0;
    const int i2 = valid ? ii : 0;
    const float* pp = pos + ((size_t)b * Np + i2) * 3;
    const float* cc = c1 + (size_t)w * 3;
    float rx = pp[0] - cc[0], ry = pp[1] - cc[1], rz = pp[2] - cc[2];
    float h1[64];
    #pragma unroll
    for (int h = 0; h < 64; ++h) {
        float4 wv = ((const float4*)w1aT)[h];
        float a = fmaf(rx, wv.x, fmaf(ry, wv.y, fmaf(rz, wv.z, wv.w)));
        h1[h] = fmaxf(a, 0.0f);
    }
    float* orow = x1 + (size_t)w * 64;
    for (int c4 = 0; c4 < 16; ++c4) {
        float v4[4];
        #pragma unroll
        for (int cq = 0; cq < 4; ++cq) {
            int c = c4 * 4 + cq;
            float acc = b1b[c];
            const float4* wr = (const float4*)(w1bT + (size_t)c * 64);
            #pragma unroll
            for (int q = 0; q < 16; ++q) {
                float4 wv = wr[q];
                acc = fmaf(h1[4 * q + 0], wv.x, acc);
                acc = fmaf(h1[4 * q + 1], wv.y, acc);
                acc = fmaf(h1[4 * q + 2], wv.z, acc);
                acc = fmaf(h1[4 * q + 3], wv.w, acc);
            }
            float v = fmaxf(acc, 0.0f);
            v = valid ? v : -__builtin_inff();
            #pragma unroll
            for (int o = 32; o > 0; o >>= 1) v = fmaxf(v, __shfl_xor(v, o, 64));
            v4[cq] = v;
        }
        if (lane == 0)
            ((float4*)orow)[c4] = make_float4(v4[0], v4[1], v4[2], v4[3]);
    }
}

// ---------------------------------------------------------------------------
// MLP2 (SA2): wave per center, lane per neighbor. [x1(64) | relpos(3)] -> 128
// relu -> 128 relu, masked max; writes x2 into X rows (cols 0..127).
// w2aT[h][0..66]=w2a[:,h], [67]=b2a[h], row stride 80. w2bT[c][h].
// ---------------------------------------------------------------------------
__global__ __launch_bounds__(256)
void mlp2_kernel(const float* __restrict__ x1, const float* __restrict__ c1,
                 const float* __restrict__ c2, const int* __restrict__ nbr2,
                 const float* __restrict__ w2aT, const float* __restrict__ w2bT,
                 const float* __restrict__ b2b, float* __restrict__ X) {
    const int lane = threadIdx.x & 63;
    int w = __builtin_amdgcn_readfirstlane((int)(blockIdx.x * 4 + (threadIdx.x >> 6)));
    const int b = w >> 9;
    const int ii = nbr2[(size_t)w * Kn + lane];
    const bool valid = ii >= 0;
    const int i2 = valid ? ii : 0;

    float x[68];
    const float4* xr = (const float4*)(x1 + ((size_t)b * M1 + i2) * 64);
    #pragma unroll
    for (int q = 0; q < 16; ++q) {
        float4 v = xr[q];
        x[4 * q + 0] = v.x; x[4 * q + 1] = v.y;
        x[4 * q + 2] = v.z; x[4 * q + 3] = v.w;
    }
    const float* cc = c2 + (size_t)w * 3;
    const float* cp = c1 + ((size_t)b * M1 + i2) * 3;
    x[64] = cp[0] - cc[0];
    x[65] = cp[1] - cc[1];
    x[66] = cp[2] - cc[2];
    x[67] = 0.0f;

    float h1[128];
    #pragma unroll
    for (int h = 0; h < 128; ++h) {
        const float4* r4 = (const float4*)(w2aT + (size_t)h * 80);
        float acc = 0.0f;
        #pragma unroll
        for (int q = 0; q < 16; ++q) {
            float4 wv = r4[q];
            acc = fmaf(x[4 * q + 0], wv.x, acc);
            acc = fmaf(x[4 * q + 1], wv.y, acc);
            acc = fmaf(x[4 * q + 2], wv.z, acc);
            acc = fmaf(x[4 * q + 3], wv.w, acc);
        }
        float4 tl = r4[16];   // w64, w65, w66, bias
        acc = fmaf(x[64], tl.x, acc);
        acc = fmaf(x[65], tl.y, acc);
        acc = fmaf(x[66], tl.z, acc);
        acc += tl.w;
        h1[h] = fmaxf(acc, 0.0f);
    }
    float* orow = X + (size_t)w * LDX;
    for (int c4 = 0; c4 < 32; ++c4) {
        float v4[4];
        #pragma unroll
        for (int cq = 0; cq < 4; ++cq) {
            int c = c4 * 4 + cq;
            float acc = b2b[c];
            const float4* wr = (const float4*)(w2bT + (size_t)c * 128);
            #pragma unroll
            for (int q = 0; q < 32; ++q) {
                float4 wv = wr[q];
                acc = fmaf(h1[4 * q + 0], wv.x, acc);
                acc = fmaf(h1[4 * q + 1], wv.y, acc);
                acc = fmaf(h1[4 * q + 2], wv.z, acc);
                acc = fmaf(h1[4 * q + 3], wv.w, acc);
            }
            float v = fmaxf(acc, 0.0f);
            v = valid ? v : -__builtin_inff();
            #pragma unroll
            for (int o = 32; o > 0; o >>= 1) v = fmaxf(v, __shfl_xor(v, o, 64));
            v4[cq] = v;
        }
        if (lane == 0) {
            orow[c4 * 4 + 0] = v4[0]; orow[c4 * 4 + 1] = v4[1];
            orow[c4 * 4 + 2] = v4[2]; orow[c4 * 4 + 3] = v4[3];
        }
    }
}

// ---------------------------------------------------------------------------
// X[:,128..130] = c2
// ---------------------------------------------------------------------------
__global__ __launch_bounds__(256)
void writec2_kernel(const float* __restrict__ c2, float* __restrict__ X) {
    int i = blockIdx.x * 256 + threadIdx.x;
    if (i < Bc * M2 * 3) {
        int w = i / 3, d = i - w * 3;
        X[(size_t)w * LDX + 128 + d] = c2[i];
    }
}

// ---------------------------------------------------------------------------
// GEMM1: H[r][c] = relu(b3a[c] + sum_i X[r][i] * w3a[i][c]), K=131.
// Block per row (uniform X row -> scalar loads), thread per channel.
// ---------------------------------------------------------------------------
__global__ __launch_bounds__(256)
void gemm1_kernel(const float* __restrict__ X, const float* __restrict__ w3a,
                  const float* __restrict__ b3a, float* __restrict__ H) {
    const int r = blockIdx.x;
    const int c = threadIdx.x;
    const float* xr = X + (size_t)r * LDX;
    float acc = b3a[c];
    for (int i = 0; i < 131; ++i)
        acc = fmaf(xr[i], w3a[(size_t)i * 256 + c], acc);
    H[(size_t)r * 256 + c] = fmaxf(acc, 0.0f);
}

// ---------------------------------------------------------------------------
// GEMM2 fused with per-tile row max: 32x64 tile, BK=32, thread = 4 rows x 2
// cols. Epilogue maxes over the 32 rows (all within one cloud) -> partial.
// Bias is added later (uniform per column, commutes with max).
// ---------------------------------------------------------------------------
__global__ __launch_bounds__(256)
void gemm2_kernel(const float* __restrict__ H, const float* __restrict__ w3b,
                  float* __restrict__ part) {
    __shared__ float As[32][33];
    __shared__ float Bs[32][64];
    __shared__ float red[8][64];
    const int bidx = blockIdx.x;
    const int nt = bidx & 15;
    const int mt = (bidx >> 4) & 15;
    const int b = bidx >> 8;
    const int row0 = b * M2 + mt * 32;
    const int col0 = nt * 64;
    const int t = threadIdx.x;
    const int rg = t >> 5, cg = t & 31;

    float acc[4][2] = {{0.f, 0.f}, {0.f, 0.f}, {0.f, 0.f}, {0.f, 0.f}};
    for (int k0 = 0; k0 < 256; k0 += 32) {
        #pragma unroll
        for (int q = 0; q < 4; ++q) {
            int id = t + q * 256;
            As[id >> 5][id & 31] = H[(size_t)(row0 + (id >> 5)) * 256 + k0 + (id & 31)];
        }
        #pragma unroll
        for (int q = 0; q < 8; ++q) {
            int id = t + q * 256;
            Bs[id >> 6][id & 63] = w3b[(size_t)(k0 + (id >> 6)) * 1024 + col0 + (id & 63)];
        }
        __syncthreads();
        #pragma unroll
        for (int kk = 0; kk < 32; ++kk) {
            float b0 = Bs[kk][cg * 2 + 0];
            float b1 = Bs[kk][cg * 2 + 1];
            #pragma unroll
            for (int j = 0; j < 4; ++j) {
                float a = As[rg * 4 + j][kk];
                acc[j][0] = fmaf(a, b0, acc[j][0]);
                acc[j][1] = fmaf(a, b1, acc[j][1]);
            }
        }
        __syncthreads();
    }
    float m0 = fmaxf(fmaxf(acc[0][0], acc[1][0]), fmaxf(acc[2][0], acc[3][0]));
    float m1 = fmaxf(fmaxf(acc[0][1], acc[1][1]), fmaxf(acc[2][1], acc[3][1]));
    red[rg][cg * 2 + 0] = m0;
    red[rg][cg * 2 + 1] = m1;
    __syncthreads();
    if (t < 64) {
        float v = red[0][t];
        #pragma unroll
        for (int q = 1; q < 8; ++q) v = fmaxf(v, red[q][t]);
        part[((size_t)b * 16 + mt) * 1024 + col0 + t] = v;
    }
}

// ---------------------------------------------------------------------------
// Final max over the 16 m-tiles per cloud + bias (no relu on last layer).
// ---------------------------------------------------------------------------
__global__ __launch_bounds__(256)
void rmax_kernel(const float* __restrict__ part, const float* __restrict__ b3b,
                 float* __restrict__ out) {
    int i = blockIdx.x * 256 + threadIdx.x;  // 8192 = B*1024
    int b = i >> 10, c = i & 1023;
    float v = -__builtin_inff();
    #pragma unroll
    for (int tt = 0; tt < 16; ++tt)
        v = fmaxf(v, part[((size_t)b * 16 + tt) * 1024 + c]);
    out[i] = v + b3b[c];
}

// ---------------------------------------------------------------------------
// Weight transposes (recomputed every call; inputs are restored each run).
// ---------------------------------------------------------------------------
__global__ __launch_bounds__(256)
void prep_kernel(const float* __restrict__ w1a, const float* __restrict__ b1a,
                 const float* __restrict__ w1b, const float* __restrict__ w2a,
                 const float* __restrict__ b2a, const float* __restrict__ w2b,
                 float* __restrict__ w1aT, float* __restrict__ w1bT,
                 float* __restrict__ w2aT, float* __restrict__ w2bT) {
    int i = blockIdx.x * 256 + threadIdx.x;  // 0..16383
    if (i < 64 * 4) {
        int h = i >> 2, d = i & 3;
        w1aT[i] = (d < 3) ? w1a[d * 64 + h] : b1a[h];
    }
    if (i < 64 * 64) {
        int c = i >> 6, h = i & 63;
        w1bT[i] = w1b[h * 64 + c];
    }
    if (i < 128 * 80) {
        int h = i / 80, d = i - h * 80;
        w2aT[i] = (d < 67) ? w2a[d * 128 + h] : ((d == 67) ? b2a[h] : 0.0f);
    }
    {
        int c = i >> 7, h = i & 127;
        w2bT[i] = w2b[h * 128 + c];
    }
}

// ---------------------------------------------------------------------------
extern "C" void kernel_launch(void* const* d_in, const int* in_sizes, int n_in,
                              void* d_out, int out_size, void* d_ws, size_t ws_size,
                              hipStream_t stream) {
    const float* pos = (const float*)d_in[0];
    const float* w1a = (const float*)d_in[1];
    const float* b1a = (const float*)d_in[2];
    const float* w1b = (const float*)d_in[3];
    const float* b1b = (const float*)d_in[4];
    const float* w2a = (const float*)d_in[5];
    const float* b2a = (const float*)d_in[6];
    const float* w2b = (const float*)d_in[7];
    const float* b2b = (const float*)d_in[8];
    const float* w3a = (const float*)d_in[9];
    const float* b3a = (const float*)d_in[10];
    const float* w3b = (const float*)d_in[11];
    const float* b3b = (const float*)d_in[12];
    float* out = (float*)d_out;

    char* ws = (char*)d_ws;
    size_t off = 0;
    auto alloc = [&](size_t bytes) -> char* {
        char* p = ws + off;
        off += (bytes + 255) & ~(size_t)255;
        return p;
    };
    float* c1   = (float*)alloc(sizeof(float) * Bc * M1 * 3);
    float* c2   = (float*)alloc(sizeof(float) * Bc * M2 * 3);
    int*   idx1 = (int*)alloc(sizeof(int) * Bc * M1);
    int*   idx2 = (int*)alloc(sizeof(int) * Bc * M2);
    int*   nbr1 = (int*)alloc(sizeof(int) * Bc * M1 * Kn);
    int*   nbr2 = (int*)alloc(sizeof(int) * Bc * M2 * Kn);
    float* x1   = (float*)alloc(sizeof(float) * Bc * M1 * 64);
    float* X    = (float*)alloc(sizeof(float) * Bc * M2 * LDX);
    float* H    = (float*)alloc(sizeof(float) * Bc * M2 * 256);
    float* part = (float*)alloc(sizeof(float) * Bc * 16 * 1024);
    float* w1aT = (float*)alloc(sizeof(float) * 64 * 4);
    float* w1bT = (float*)alloc(sizeof(float) * 64 * 64);
    float* w2aT = (float*)alloc(sizeof(float) * 128 * 80);
    float* w2bT = (float*)alloc(sizeof(float) * 128 * 128);

    prep_kernel<<<dim3(64), dim3(256), 0, stream>>>(w1a, b1a, w1b, w2a, b2a, w2b,
                                                    w1aT, w1bT, w2aT, w2bT);
    fps_kernel<Np><<<dim3(Bc), dim3(512), 0, stream>>>(pos, M1, idx1, c1);
    bq_kernel<Np><<<dim3(Bc * M1 / 4), dim3(256), 0, stream>>>(
        pos, c1, 11, (float)(0.2 * 0.2), nbr1);
    mlp1_kernel<<<dim3(Bc * M1 / 4), dim3(256), 0, stream>>>(
        pos, c1, nbr1, w1aT, w1bT, b1b, x1);
    fps_kernel<M1><<<dim3(Bc), dim3(512), 0, stream>>>(c1, M2, idx2, c2);
    bq_kernel<M1><<<dim3(Bc * M2 / 4), dim3(256), 0, stream>>>(
        c1, c2, 9, (float)(0.4 * 0.4), nbr2);
    mlp2_kernel<<<dim3(Bc * M2 / 4), dim3(256), 0, stream>>>(
        x1, c1, c2, nbr2, w2aT, w2bT, b2b, X);
    writec2_kernel<<<dim3(48), dim3(256), 0, stream>>>(c2, X);
    gemm1_kernel<<<dim3(Bc * M2), dim3(256), 0, stream>>>(X, w3a, b3a, H);
    gemm2_kernel<<<dim3(Bc * 16 * 16), dim3(256), 0, stream>>>(H, w3b, part);
    rmax_kernel<<<dim3(32), dim3(256), 0, stream>>>(part, b3b, out);
}